// Round 6
// baseline (131.077 us; speedup 1.0000x reference)
//
#include <hip/hip_runtime.h>
#include <cstdint>
#include <math.h>

#define KN 128
#define BATCH 16
#define CAND 64

typedef float vfloat4 __attribute__((ext_vector_type(4)));

// Output layout (floats), in reference return order:
// tokens (B,C,4) | rel (B,C,K,K) | acyclic (B,C) | dists (2,B,K,K)
static constexpr size_t TOK_OFF = 0;
static constexpr size_t REL_OFF = (size_t)BATCH * CAND * 4;                     // 4096
static constexpr size_t ACY_OFF = REL_OFF + (size_t)BATCH * CAND * KN * KN;    // 16781312
static constexpr size_t DST_OFF = ACY_OFF + (size_t)BATCH * CAND;              // 16782336

// Diagonal sentinel for dmin: must be large but FINITE after a bf16 round-trip
// (FLT_MAX rounds up to +inf in bf16 -> |inf-inf|=nan in the checker).
#define DIAG_BIG 1.0e30f

// Workspace layout (uint32 words):
//   [0, 2048)              : base bits (B*K*4 words = 8 KB), written by prep
//   [2048, 2048 + 1024*1024): bitplanes, 1024 words per (b,c):
//       [0,512)  = adj  flat (row i, word k at i*4+k)
//       [512,1024)= adjT flat
static constexpr size_t WS_BITS  = 0;
static constexpr size_t WS_PLANE = 2048;

// ---------------- Kernel A: base bits prepass + dists ----------------
__global__ __launch_bounds__(256) void prep_kernel(const float* __restrict__ A_t,
                                                   const float* __restrict__ feat,
                                                   uint32_t* __restrict__ bits,
                                                   float* __restrict__ out) {
    int t = threadIdx.x;
    // base bits: 4096 half-rows across 1024 blocks
    {
        int tid  = blockIdx.x * 256 + t;
        int wave = tid >> 6;
        int lane = tid & 63;
        int half = wave & 1;
        int row  = wave >> 1;       // b*128 + i
        float v = A_t[(size_t)row * KN + half * 64 + lane];
        unsigned long long m = __ballot(v > 0.5f);
        if (lane == 0) {
            bits[row * 4 + half * 2]     = (uint32_t)m;
            bits[row * 4 + half * 2 + 1] = (uint32_t)(m >> 32);
        }
    }
    // dists: 2 rows per block
    {
        int bi = 2 * blockIdx.x + (t >> 7);    // 0..2047 = b*K + i
        int b2 = bi >> 7, i = bi & 127, j = t & 127;
        const float* fi = feat + (size_t)bi * 6;
        const float* fj = feat + (size_t)(b2 * KN + j) * 6;
        float pix = fi[0], piy = fi[1], vix = fi[3], viy = fi[4];
        float pjx = fj[0], pjy = fj[1], vjx = fj[3], vjy = fj[4];
        float dx = pix - pjx, dy = piy - pjy;
        float d = sqrtf(dx * dx + dy * dy);
        float rx = pjx - pix, ry = pjy - piy;
        float vx = vjx - vix, vy = vjy - viy;
        float vv = vx * vx + vy * vy;
        float rv = rx * vx + ry * vy;
        float ts = fminf(fmaxf(-rv / (vv + 1e-6f), 0.0f), 3.0f);
        float mx = rx + vx * ts, my = ry + vy * ts;
        float dmin = (i == j) ? DIAG_BIG : sqrtf(mx * mx + my * my);
        float* o = out + DST_OFF;
        __builtin_nontemporal_store(d,    o + (size_t)(b2 * KN + i) * KN + j);
        __builtin_nontemporal_store(dmin, o + (size_t)((BATCH + b2) * KN + i) * KN + j);
    }
}

// ---------------- Kernel B: read cand -> bitplanes + logic ----------------
// Nearly pure-read kernel: 67 MB cand in, 4 MB bitplanes out (plain stores,
// L2-resident for kernel C), plus tokens/acyclic. No big store phase, so
// blocks retire asynchronously — no intra-block read/write serialization.
__global__ __launch_bounds__(256) void pack_kernel(const float* __restrict__ cand,
                                                   const float* __restrict__ mask,
                                                   const uint32_t* __restrict__ baseBits,
                                                   uint32_t* __restrict__ planes,
                                                   float* __restrict__ out) {
    __shared__ uint32_t adj[KN][5];
    __shared__ uint32_t adjT[KN][6];
    __shared__ uint32_t baseB[KN][4];
    __shared__ uint32_t validW[4];
    __shared__ uint32_t remW2[2][4];
    __shared__ uint32_t removedW[4];
    __shared__ int      minIdx;

    const int t    = threadIdx.x;
    const int lane = t & 63;
    const int wave = t >> 6;
    const int bc   = blockIdx.x;        // b*64 + c
    const int b    = bc >> 6;

    const float* cptr = cand + (size_t)bc * (KN * KN);

    // Issue ALL cand loads first (16-deep MLP), retire under independent work
    float4 c[16];
    const int sub = lane & 31;
    #pragma unroll
    for (int m = 0; m < 16; ++m) {
        int r = (m * 4 + wave) * 2 + (lane >> 5);
        c[m] = ((const float4*)(cptr + (size_t)r * KN))[sub];
    }

    if (t == 0) minIdx = 0x7fffffff;
    if (t < 4)  removedW[t] = 0;

    // base bitmask: 512 words (L2-hot, written by prep_kernel)
    for (int w = t; w < 512; w += 256) {
        baseB[w >> 2][w & 3] = baseBits[b * 512 + w];
    }

    // valid mask: wave0 -> nodes 0..63, wave1 -> 64..127
    if (wave < 2) {
        float mv = mask[b * KN + wave * 64 + lane];
        unsigned long long m = __ballot(mv > 0.5f);
        if (lane == 0) {
            validW[wave * 2]     = (uint32_t)m;
            validW[wave * 2 + 1] = (uint32_t)(m >> 32);
        }
    }

    // Pack candidate adjacency rows into LDS
    #pragma unroll
    for (int m = 0; m < 16; ++m) {
        int r = (m * 4 + wave) * 2 + (lane >> 5);
        const float4 v = c[m];
        uint32_t nib = (v.x > 0.5f ? 1u : 0u) | (v.y > 0.5f ? 2u : 0u) |
                       (v.z > 0.5f ? 4u : 0u) | (v.w > 0.5f ? 8u : 0u);
        uint32_t word = nib << (4 * (sub & 7));
        word |= __shfl_xor(word, 1);
        word |= __shfl_xor(word, 2);
        word |= __shfl_xor(word, 4);
        if ((lane & 7) == 0) adj[r][sub >> 3] = word;
    }
    __syncthreads();   // adj, baseB, validW ready

    // 64x64 bit-tile transpose via 6-step shfl_xor butterfly (verified R5).
    {
        const int h = wave >> 1, q = wave & 1;
        uint32_t lo = adj[h * 64 + lane][q * 2];
        uint32_t hi = adj[h * 64 + lane][q * 2 + 1];
        unsigned long long x = ((unsigned long long)hi << 32) | lo;
        const unsigned long long Lm[6] = {
            0x5555555555555555ull, 0x3333333333333333ull, 0x0F0F0F0F0F0F0F0Full,
            0x00FF00FF00FF00FFull, 0x0000FFFF0000FFFFull, 0x00000000FFFFFFFFull };
        #pragma unroll
        for (int k = 0; k < 6; ++k) {
            const int d = 1 << k;
            const unsigned long long L = Lm[k];
            unsigned long long y = __shfl_xor((unsigned long long)x, d);
            x = (lane & d) ? ((x & ~L) | ((y & ~L) >> d))
                           : ((x & L)  | ((y & L) << d));
        }
        adjT[q * 64 + lane][2 * h]     = (uint32_t)x;
        adjT[q * 64 + lane][2 * h + 1] = (uint32_t)(x >> 32);
    }
    __syncthreads();   // adjT ready

    // ---- bitplane store: 4 KB/block, plain stores (want L2 residency) ----
    {
        uint32_t* pb = planes + (size_t)bc * 1024;
        #pragma unroll
        for (int rep = 0; rep < 2; ++rep) {
            int w = t + rep * 256;
            pb[w]       = adj[w >> 2][w & 3];
            pb[512 + w] = adjT[w >> 2][w & 3];
        }
    }

    // ---- logic (token scan + Kahn + acyclic) ----
    for (int idx = t; idx < 512; idx += 256) {
        int i = idx >> 2, k = idx & 3;
        uint32_t diff = adj[i][k] ^ baseB[i][k];
        if (diff) {
            int base = k * 32;
            uint32_t up, low;
            if (i < base)            { up = diff; low = 0u; }
            else if (i >= base + 31) { up = 0u; low = (i > base + 31) ? diff : (diff & 0x7fffffffu); }
            else {
                int s = i - base;    // 1..30
                up  = diff & (0xffffffffu << (s + 1));
                low = diff & ((1u << s) - 1u);
            }
            int c1 = 0x7fffffff, c2 = 0x7fffffff;
            if (up)  c1 = (i << 7) | (base + __builtin_ctz(up));
            if (low) { int cc2 = base + __builtin_ctz(low); c2 = (cc2 << 7) | i; }
            int cm = min(c1, c2);
            if (cm != 0x7fffffff) atomicMin(&minIdx, cm);
        }
    }
    __syncthreads();   // minIdx final

    if (t == 0) {
        float* tok = out + TOK_OFF + (size_t)bc * 4;
        int mi = minIdx;
        if (mi != 0x7fffffff) {
            int i = mi >> 7, j = mi & 127;
            uint32_t b_ij = (baseB[i][j >> 5] >> (j & 31)) & 1u;
            uint32_t b_ji = (baseB[j][i >> 5] >> (i & 31)) & 1u;
            uint32_t c_ij = (adj[i][j >> 5] >> (j & 31)) & 1u;
            uint32_t c_ji = (adj[j][i >> 5] >> (i & 31)) & 1u;
            int prev = (b_ij && !b_ji) ? 1 : ((b_ji && !b_ij) ? 2 : 0);
            int nxt  = (c_ij && !c_ji) ? 1 : ((c_ji && !c_ij) ? 2 : 0);
            tok[0] = (float)i; tok[1] = (float)j; tok[2] = (float)prev; tok[3] = (float)nxt;
        } else {
            tok[0] = 0.f; tok[1] = 0.f; tok[2] = 0.f; tok[3] = 0.f;
        }
    }

    // Per-node registers for Kahn (nodes on threads 0..127)
    uint32_t cT0 = 0, cT1 = 0, cT2 = 0, cT3 = 0;
    int  indeg = 0;
    bool validT = false;
    if (t < KN) {
        cT0 = adjT[t][0]; cT1 = adjT[t][1]; cT2 = adjT[t][2]; cT3 = adjT[t][3];
        validT = (validW[t >> 5] >> (t & 31)) & 1u;
        indeg = validT ? (__popc(cT0) + __popc(cT1) + __popc(cT2) + __popc(cT3)) : 0;
    }

    // Kahn peeling, double-buffered remW2: ONE barrier per iteration
    // (hazard audit: iter it reads remW2[it&1] post-sync; next write to that
    // buffer is at it+2, after it+1's sync). Verified correct in R5.
    bool removed = false;
    for (int it = 0; it < KN; ++it) {
        const int bsel = it & 1;
        bool rem = (t < KN) && validT && !removed && (indeg == 0);
        unsigned long long m = __ballot(rem);
        if (wave < 2 && lane == 0) {
            remW2[bsel][wave * 2]     = (uint32_t)m;
            remW2[bsel][wave * 2 + 1] = (uint32_t)(m >> 32);
        }
        __syncthreads();
        uint32_t r0 = remW2[bsel][0], r1 = remW2[bsel][1];
        uint32_t r2 = remW2[bsel][2], r3 = remW2[bsel][3];
        if ((r0 | r1 | r2 | r3) == 0u) break;   // block-uniform
        if (t < 4) removedW[t] |= remW2[bsel][t];
        if (t < KN) {
            indeg -= __popc(r0 & cT0) + __popc(r1 & cT1) +
                     __popc(r2 & cT2) + __popc(r3 & cT3);
            removed = removed || rem;
        }
    }
    __syncthreads();   // removedW final

    if (t == 0) {
        int rc = __popc(removedW[0]) + __popc(removedW[1]) + __popc(removedW[2]) + __popc(removedW[3]);
        int vc = __popc(validW[0]) + __popc(validW[1]) + __popc(validW[2]) + __popc(validW[3]);
        out[ACY_OFF + bc] = ((rc == vc) || (vc <= 1)) ? 1.0f : 0.0f;
    }
}

// ---------------- Kernel C: pure rel store-stream ----------------
// Reads 4 KB of bitplanes (L2-hot, written by pack_kernel), expands to
// 64 KB of rel floats via NT stores. Structurally identical to the harness
// fill that measurably sustains 6.3 TB/s — the diagnostic for whether
// read/write mixing was main_kernel's 3.0 TB/s cap.
__global__ __launch_bounds__(256) void rel_kernel(const uint32_t* __restrict__ planes,
                                                  float* __restrict__ out) {
    __shared__ uint32_t plane[1024];   // [0,512)=adj flat, [512,1024)=adjT flat

    const int t  = threadIdx.x;
    const int bc = blockIdx.x;

    // 16 B per thread, coalesced: the whole 4 KB plane
    uint4 v = ((const uint4*)(planes + (size_t)bc * 1024))[t];
    ((uint4*)plane)[t] = v;
    __syncthreads();

    float* relp = out + REL_OFF + (size_t)bc * (KN * KN);
    #pragma unroll
    for (int m = 0; m < 16; ++m) {
        int q  = t + 256 * m;        // float4 index 0..4095
        int i  = q >> 5;             // row
        int j0 = (q & 31) * 4;       // starting col
        int iw = j0 >> 5, sh = j0 & 31;
        uint32_t wij = plane[i * 4 + iw];          // cb[i][j0..]
        uint32_t wti = plane[512 + i * 4 + iw];    // cb[j0..][i]
        uint32_t a4 = (wij >> sh) & 0xFu;
        uint32_t b4 = (wti >> sh) & 0xFu;
        uint32_t packed = ((a4 * 0x00204081u) & 0x01010101u)
                        | (((b4 * 0x00204081u) & 0x01010101u) << 1);
        vfloat4 o;
        o.x = (float)(uint8_t)(packed);
        o.y = (float)(uint8_t)(packed >> 8);
        o.z = (float)(uint8_t)(packed >> 16);
        o.w = (float)(uint8_t)(packed >> 24);
        __builtin_nontemporal_store(o, ((vfloat4*)relp) + q);
    }
}

extern "C" void kernel_launch(void* const* d_in, const int* in_sizes, int n_in,
                              void* d_out, int out_size, void* d_ws, size_t ws_size,
                              hipStream_t stream) {
    const float* A_t  = (const float*)d_in[0];
    const float* cand = (const float*)d_in[1];
    const float* feat = (const float*)d_in[2];
    const float* mask = (const float*)d_in[3];
    float* out = (float*)d_out;
    uint32_t* ws   = (uint32_t*)d_ws;
    uint32_t* bits   = ws + WS_BITS;    // 8 KB
    uint32_t* planes = ws + WS_PLANE;   // 4 MB

    prep_kernel<<<1024, 256, 0, stream>>>(A_t, feat, bits, out);
    pack_kernel<<<BATCH * CAND, 256, 0, stream>>>(cand, mask, bits, planes, out);
    rel_kernel<<<BATCH * CAND, 256, 0, stream>>>(planes, out);
}

// Round 7
// 123.200 us; speedup vs baseline: 1.0639x; 1.0639x over previous
//
#include <hip/hip_runtime.h>
#include <cstdint>
#include <math.h>

#define KN 128
#define BATCH 16
#define CAND 64

typedef float vfloat4 __attribute__((ext_vector_type(4)));

// Output layout (floats), in reference return order:
// tokens (B,C,4) | rel (B,C,K,K) | acyclic (B,C) | dists (2,B,K,K)
static constexpr size_t TOK_OFF = 0;
static constexpr size_t REL_OFF = (size_t)BATCH * CAND * 4;                     // 4096
static constexpr size_t ACY_OFF = REL_OFF + (size_t)BATCH * CAND * KN * KN;    // 16781312
static constexpr size_t DST_OFF = ACY_OFF + (size_t)BATCH * CAND;              // 16782336

// Diagonal sentinel for dmin: must be large but FINITE after a bf16 round-trip
// (FLT_MAX rounds up to +inf in bf16 -> |inf-inf|=nan in the checker).
#define DIAG_BIG 1.0e30f

// ---------------- Fused kernel: one 256-thread block per (b,c) ----------------
// R7 = R3's verified-best structure (120.1 us; parity stagger on bc&1,
// ballot transpose, 2-barrier Kahn — all byte-identical) + prep_kernel fused
// in. This deletes one dispatch + inter-kernel gap + prep's tail drain, the
// only cost item never isolated on the best base. Each block:
//   - computes its 2 dist rows under the cand-load shadow (R2-verified),
//   - packs baseB from A_t directly (64 blocks share each 1 MB A_t slice ->
//     L2-served; a[16] is issued after c[16] dies so VGPR peaks don't stack).
__global__ __launch_bounds__(256) void fused_kernel(const float* __restrict__ A_t,
                                                    const float* __restrict__ cand,
                                                    const float* __restrict__ feat,
                                                    const float* __restrict__ mask,
                                                    float* __restrict__ out) {
    __shared__ uint32_t adj[KN][5];     // row bitmask: adj[i][w] bit k = cb[i][32w+k]
    __shared__ uint32_t adjT[KN][6];    // col bitmask: adjT[c][w] bit k = cb[32w+k][c]
    __shared__ uint32_t baseB[KN][4];
    __shared__ uint32_t validW[4];
    __shared__ uint32_t remW[4];
    __shared__ uint32_t removedW[4];
    __shared__ int      minIdx;

    const int t    = threadIdx.x;
    const int lane = t & 63;
    const int wave = t >> 6;
    const int bc   = blockIdx.x;        // b*64 + c
    const int b    = bc >> 6;

    const float* cptr = cand + (size_t)bc * (KN * KN);
    const float* aptr = A_t  + (size_t)b  * (KN * KN);
    float* relp = out + REL_OFF + (size_t)bc * (KN * KN);

    // ---- dist feat loads first: their latency hides under the c-load issue --
    const int bi = 2 * bc + (t >> 7);    // b*128 + i, covers all (b,i) exactly once
    const int b2 = bi >> 7, di = bi & 127, dj = t & 127;
    const float* fi = feat + (size_t)bi * 6;
    const float* fj = feat + (size_t)(b2 * KN + dj) * 6;
    float pix = fi[0], piy = fi[1], vix = fi[3], viy = fi[4];
    float pjx = fj[0], pjy = fj[1], vjx = fj[3], vjy = fj[4];

    // ---- issue ALL cand loads (16-deep MLP) ----
    float4 c[16];
    const int sub = lane & 31;
    #pragma unroll
    for (int m = 0; m < 16; ++m) {
        int r = (m * 4 + wave) * 2 + (lane >> 5);
        c[m] = ((const float4*)(cptr + (size_t)r * KN))[sub];
    }

    if (t == 0) minIdx = 0x7fffffff;
    if (t < 4)  removedW[t] = 0;

    // valid mask: wave0 -> nodes 0..63, wave1 -> 64..127
    if (wave < 2) {
        float mv = mask[b * KN + wave * 64 + lane];
        unsigned long long m = __ballot(mv > 0.5f);
        if (lane == 0) {
            validW[wave * 2]     = (uint32_t)m;
            validW[wave * 2 + 1] = (uint32_t)(m >> 32);
        }
    }

    // ---- dist compute + NT stores (consumes only feat values) ----
    {
        float dx = pix - pjx, dy = piy - pjy;
        float d = sqrtf(dx * dx + dy * dy);
        float rx = pjx - pix, ry = pjy - piy;
        float vx = vjx - vix, vy = vjy - viy;
        float vv = vx * vx + vy * vy;
        float rv = rx * vx + ry * vy;
        float ts = fminf(fmaxf(-rv / (vv + 1e-6f), 0.0f), 3.0f);
        float mx = rx + vx * ts, my = ry + vy * ts;
        float dmin = (di == dj) ? DIAG_BIG : sqrtf(mx * mx + my * my);
        float* o = out + DST_OFF;
        __builtin_nontemporal_store(d,    o + (size_t)(b2 * KN + di) * KN + dj);
        __builtin_nontemporal_store(dmin, o + (size_t)((BATCH + b2) * KN + di) * KN + dj);
    }

    // ---- pack candidate adjacency rows into LDS (c[] dies here) ----
    #pragma unroll
    for (int m = 0; m < 16; ++m) {
        int r = (m * 4 + wave) * 2 + (lane >> 5);
        const float4 v = c[m];
        uint32_t nib = (v.x > 0.5f ? 1u : 0u) | (v.y > 0.5f ? 2u : 0u) |
                       (v.z > 0.5f ? 4u : 0u) | (v.w > 0.5f ? 8u : 0u);
        uint32_t word = nib << (4 * (sub & 7));
        word |= __shfl_xor(word, 1);
        word |= __shfl_xor(word, 2);
        word |= __shfl_xor(word, 4);
        if ((lane & 7) == 0) adj[r][sub >> 3] = word;
    }

    // ---- issue A_t loads (L2-hot); latency hides under the transpose ----
    float4 a[16];
    #pragma unroll
    for (int m = 0; m < 16; ++m) {
        int r = (m * 4 + wave) * 2 + (lane >> 5);
        a[m] = ((const float4*)(aptr + (size_t)r * KN))[sub];
    }

    __syncthreads();   // adj, validW, inits ready

    // Ballot bit-transpose: wave w -> rows [h*64,..), cols [q*64,..)  (R3 exact)
    {
        const int h = wave >> 1, q = wave & 1;
        uint32_t rw0 = adj[h * 64 + lane][q * 2];
        uint32_t rw1 = adj[h * 64 + lane][q * 2 + 1];
        uint32_t myLo = 0, myHi = 0;
        #pragma unroll
        for (int cc = 0; cc < 64; ++cc) {
            uint32_t w = (cc < 32) ? rw0 : rw1;
            unsigned long long m = __ballot((w >> (cc & 31)) & 1u);
            if (lane == cc) { myLo = (uint32_t)m; myHi = (uint32_t)(m >> 32); }
        }
        adjT[q * 64 + lane][2 * h]     = myLo;
        adjT[q * 64 + lane][2 * h + 1] = myHi;
    }

    // ---- pack base adjacency rows (consumes a[], landed during transpose) ----
    #pragma unroll
    for (int m = 0; m < 16; ++m) {
        int r = (m * 4 + wave) * 2 + (lane >> 5);
        const float4 v = a[m];
        uint32_t nib = (v.x > 0.5f ? 1u : 0u) | (v.y > 0.5f ? 2u : 0u) |
                       (v.z > 0.5f ? 4u : 0u) | (v.w > 0.5f ? 8u : 0u);
        uint32_t word = nib << (4 * (sub & 7));
        word |= __shfl_xor(word, 1);
        word |= __shfl_xor(word, 2);
        word |= __shfl_xor(word, 4);
        if ((lane & 7) == 0) baseB[r][sub >> 3] = word;
    }

    __syncthreads();   // adjT + baseB ready

    // Per-node registers for Kahn (nodes on threads 0..127)
    uint32_t cT0 = 0, cT1 = 0, cT2 = 0, cT3 = 0;
    int  indeg = 0;
    bool validT = false;
    if (t < KN) {
        cT0 = adjT[t][0]; cT1 = adjT[t][1]; cT2 = adjT[t][2]; cT3 = adjT[t][3];
        validT = (validW[t >> 5] >> (t & 31)) & 1u;
        indeg = validT ? (__popc(cT0) + __popc(cT1) + __popc(cT2) + __popc(cT3)) : 0;
    }

    // ================= phase bodies (as lambdas; block-uniform call order) ====
    auto rel_expand = [&]() {
        // Bit->float via multiply-spread into a byte-packed word; clang emits
        // v_cvt_f32_ubyte{0..3} for (float)(uint8_t)(x>>8k).
        #pragma unroll
        for (int m = 0; m < 16; ++m) {
            int q  = t + 256 * m;        // float4 index 0..4095
            int i  = q >> 5;             // row
            int j0 = (q & 31) * 4;       // starting col
            int iw = j0 >> 5, sh = j0 & 31;
            uint32_t wij = adj[i][iw];           // cb[i][j0..]
            uint32_t wti = adjT[i][iw];          // cb[j0..][i]
            uint32_t a4 = (wij >> sh) & 0xFu;
            uint32_t b4 = (wti >> sh) & 0xFu;
            uint32_t packed = ((a4 * 0x00204081u) & 0x01010101u)
                            | (((b4 * 0x00204081u) & 0x01010101u) << 1);
            vfloat4 o;
            o.x = (float)(uint8_t)(packed);
            o.y = (float)(uint8_t)(packed >> 8);
            o.z = (float)(uint8_t)(packed >> 16);
            o.w = (float)(uint8_t)(packed >> 24);
            __builtin_nontemporal_store(o, ((vfloat4*)relp) + q);
        }
    };

    auto logic_phase = [&]() {
        // Edit-token scan: min linear index of differing upper-triangle pair
        for (int idx = t; idx < 512; idx += 256) {
            int i = idx >> 2, k = idx & 3;
            uint32_t diff = adj[i][k] ^ baseB[i][k];
            if (diff) {
                int base = k * 32;
                uint32_t up, low;
                if (i < base)            { up = diff; low = 0u; }
                else if (i >= base + 31) { up = 0u; low = (i > base + 31) ? diff : (diff & 0x7fffffffu); }
                else {
                    int s = i - base;    // 1..30
                    up  = diff & (0xffffffffu << (s + 1));
                    low = diff & ((1u << s) - 1u);
                }
                int c1 = 0x7fffffff, c2 = 0x7fffffff;
                if (up)  c1 = (i << 7) | (base + __builtin_ctz(up));
                if (low) { int cc2 = base + __builtin_ctz(low); c2 = (cc2 << 7) | i; }
                int cm = min(c1, c2);
                if (cm != 0x7fffffff) atomicMin(&minIdx, cm);
            }
        }
        __syncthreads();   // minIdx final

        // Token write
        if (t == 0) {
            float* tok = out + TOK_OFF + (size_t)bc * 4;
            int mi = minIdx;
            if (mi != 0x7fffffff) {
                int i = mi >> 7, j = mi & 127;
                uint32_t b_ij = (baseB[i][j >> 5] >> (j & 31)) & 1u;
                uint32_t b_ji = (baseB[j][i >> 5] >> (i & 31)) & 1u;
                uint32_t c_ij = (adj[i][j >> 5] >> (j & 31)) & 1u;
                uint32_t c_ji = (adj[j][i >> 5] >> (i & 31)) & 1u;
                int prev = (b_ij && !b_ji) ? 1 : ((b_ji && !b_ij) ? 2 : 0);
                int nxt  = (c_ij && !c_ji) ? 1 : ((c_ji && !c_ij) ? 2 : 0);
                tok[0] = (float)i; tok[1] = (float)j; tok[2] = (float)prev; tok[3] = (float)nxt;
            } else {
                tok[0] = 0.f; tok[1] = 0.f; tok[2] = 0.f; tok[3] = 0.f;
            }
        }

        // Kahn peeling: dec via popc of column masks (early-exit = fixed point)
        bool removed = false;
        for (int it = 0; it < KN; ++it) {
            bool rem = (t < KN) && validT && !removed && (indeg == 0);
            unsigned long long m = __ballot(rem);
            if (wave < 2 && lane == 0) {
                remW[wave * 2]     = (uint32_t)m;
                remW[wave * 2 + 1] = (uint32_t)(m >> 32);
            }
            __syncthreads();
            uint32_t r0 = remW[0], r1 = remW[1], r2 = remW[2], r3 = remW[3];
            if ((r0 | r1 | r2 | r3) == 0u) break;
            if (t < 4) removedW[t] |= remW[t];
            if (t < KN) {
                indeg -= __popc(r0 & cT0) + __popc(r1 & cT1) +
                         __popc(r2 & cT2) + __popc(r3 & cT3);
                removed = removed || rem;
            }
            __syncthreads();
        }
        __syncthreads();

        if (t == 0) {
            int rc = __popc(removedW[0]) + __popc(removedW[1]) + __popc(removedW[2]) + __popc(removedW[3]);
            int vc = __popc(validW[0]) + __popc(validW[1]) + __popc(validW[2]) + __popc(validW[3]);
            out[ACY_OFF + bc] = ((rc == vc) || (vc <= 1)) ? 1.0f : 0.0f;
        }
    };

    // Parity stagger (block-uniform branch: __syncthreads inside is safe)
    if ((bc & 1) == 0) {
        rel_expand();
        logic_phase();
    } else {
        logic_phase();
        rel_expand();
    }
}

extern "C" void kernel_launch(void* const* d_in, const int* in_sizes, int n_in,
                              void* d_out, int out_size, void* d_ws, size_t ws_size,
                              hipStream_t stream) {
    const float* A_t  = (const float*)d_in[0];
    const float* cand = (const float*)d_in[1];
    const float* feat = (const float*)d_in[2];
    const float* mask = (const float*)d_in[3];
    float* out = (float*)d_out;
    (void)d_ws; (void)ws_size;

    fused_kernel<<<BATCH * CAND, 256, 0, stream>>>(A_t, cand, feat, mask, out);
}

// Round 8
// 120.795 us; speedup vs baseline: 1.0851x; 1.0199x over previous
//
#include <hip/hip_runtime.h>
#include <cstdint>
#include <math.h>

#define KN 128
#define BATCH 16
#define CAND 64

typedef float vfloat4 __attribute__((ext_vector_type(4)));

// Output layout (floats), in reference return order:
// tokens (B,C,4) | rel (B,C,K,K) | acyclic (B,C) | dists (2,B,K,K)
static constexpr size_t TOK_OFF = 0;
static constexpr size_t REL_OFF = (size_t)BATCH * CAND * 4;                     // 4096
static constexpr size_t ACY_OFF = REL_OFF + (size_t)BATCH * CAND * KN * KN;    // 16781312
static constexpr size_t DST_OFF = ACY_OFF + (size_t)BATCH * CAND;              // 16782336

// Diagonal sentinel for dmin: must be large but FINITE after a bf16 round-trip
// (FLT_MAX rounds up to +inf in bf16 -> |inf-inf|=nan in the checker).
#define DIAG_BIG 1.0e30f

// ---------------- Kernel A: base bits prepass + dists ----------------
__global__ __launch_bounds__(256) void prep_kernel(const float* __restrict__ A_t,
                                                   const float* __restrict__ feat,
                                                   uint32_t* __restrict__ bits,
                                                   float* __restrict__ out) {
    int t = threadIdx.x;
    // base bits: 4096 half-rows across 1024 blocks
    {
        int tid  = blockIdx.x * 256 + t;
        int wave = tid >> 6;
        int lane = tid & 63;
        int half = wave & 1;
        int row  = wave >> 1;       // b*128 + i
        float v = A_t[(size_t)row * KN + half * 64 + lane];
        unsigned long long m = __ballot(v > 0.5f);
        if (lane == 0) {
            bits[row * 4 + half * 2]     = (uint32_t)m;
            bits[row * 4 + half * 2 + 1] = (uint32_t)(m >> 32);
        }
    }
    // dists: 2 rows per block
    {
        int bi = 2 * blockIdx.x + (t >> 7);    // 0..2047 = b*K + i
        int b2 = bi >> 7, i = bi & 127, j = t & 127;
        const float* fi = feat + (size_t)bi * 6;
        const float* fj = feat + (size_t)(b2 * KN + j) * 6;
        float pix = fi[0], piy = fi[1], vix = fi[3], viy = fi[4];
        float pjx = fj[0], pjy = fj[1], vjx = fj[3], vjy = fj[4];
        float dx = pix - pjx, dy = piy - pjy;
        float d = sqrtf(dx * dx + dy * dy);
        float rx = pjx - pix, ry = pjy - piy;
        float vx = vjx - vix, vy = vjy - viy;
        float vv = vx * vx + vy * vy;
        float rv = rx * vx + ry * vy;
        float ts = fminf(fmaxf(-rv / (vv + 1e-6f), 0.0f), 3.0f);
        float mx = rx + vx * ts, my = ry + vy * ts;
        float dmin = (i == j) ? DIAG_BIG : sqrtf(mx * mx + my * my);
        float* o = out + DST_OFF;
        __builtin_nontemporal_store(d,    o + (size_t)(b2 * KN + i) * KN + j);
        __builtin_nontemporal_store(dmin, o + (size_t)((BATCH + b2) * KN + i) * KN + j);
    }
}

// ---------------- Main kernel: one 256-thread block per (b,c) ----------------
// Parity-staggered phase order (verified best: 120.8/121.0/120.1 across three
// runs; all seven structural deviations — wave-spec, full fusion, pair
// pipeline, bit8 stagger, 3-way split, prep fusion — regressed 3-11 us).
// Even blocks store rel FIRST then do Kahn; odd blocks do Kahn first then
// store rel. Co-resident blocks thus overlap store-phase with logic-phase,
// spreading the NT-store stream across the whole kernel.
__global__ __launch_bounds__(256) void main_kernel(const float* __restrict__ cand,
                                                   const float* __restrict__ mask,
                                                   const uint32_t* __restrict__ baseBits,
                                                   float* __restrict__ out) {
    __shared__ uint32_t adj[KN][5];     // row bitmask: adj[i][w] bit k = cb[i][32w+k]
    __shared__ uint32_t adjT[KN][6];    // col bitmask: adjT[c][w] bit k = cb[32w+k][c]
    __shared__ uint32_t baseB[KN][4];
    __shared__ uint32_t validW[4];
    __shared__ uint32_t remW[4];
    __shared__ uint32_t removedW[4];
    __shared__ int      minIdx;

    const int t    = threadIdx.x;
    const int lane = t & 63;
    const int wave = t >> 6;
    const int bc   = blockIdx.x;        // b*64 + c
    const int b    = bc >> 6;

    const float* cptr = cand + (size_t)bc * (KN * KN);
    float* relp = out + REL_OFF + (size_t)bc * (KN * KN);

    // Issue ALL cand loads first (16-deep MLP), retire under independent work
    float4 c[16];
    const int sub = lane & 31;
    #pragma unroll
    for (int m = 0; m < 16; ++m) {
        int r = (m * 4 + wave) * 2 + (lane >> 5);
        c[m] = ((const float4*)(cptr + (size_t)r * KN))[sub];
    }

    if (t == 0) minIdx = 0x7fffffff;
    if (t < 4)  removedW[t] = 0;

    // base bitmask: 512 words (L2-hot, written by prep_kernel)
    for (int w = t; w < 512; w += 256) {
        baseB[w >> 2][w & 3] = baseBits[b * 512 + w];
    }

    // valid mask: wave0 -> nodes 0..63, wave1 -> 64..127
    if (wave < 2) {
        float mv = mask[b * KN + wave * 64 + lane];
        unsigned long long m = __ballot(mv > 0.5f);
        if (lane == 0) {
            validW[wave * 2]     = (uint32_t)m;
            validW[wave * 2 + 1] = (uint32_t)(m >> 32);
        }
    }

    // Pack candidate adjacency rows into LDS
    #pragma unroll
    for (int m = 0; m < 16; ++m) {
        int r = (m * 4 + wave) * 2 + (lane >> 5);
        const float4 v = c[m];
        uint32_t nib = (v.x > 0.5f ? 1u : 0u) | (v.y > 0.5f ? 2u : 0u) |
                       (v.z > 0.5f ? 4u : 0u) | (v.w > 0.5f ? 8u : 0u);
        uint32_t word = nib << (4 * (sub & 7));
        word |= __shfl_xor(word, 1);
        word |= __shfl_xor(word, 2);
        word |= __shfl_xor(word, 4);
        if ((lane & 7) == 0) adj[r][sub >> 3] = word;
    }
    __syncthreads();   // adj, baseB, validW ready

    // Ballot bit-transpose: wave w -> rows [h*64,..), cols [q*64,..)
    {
        const int h = wave >> 1, q = wave & 1;
        uint32_t rw0 = adj[h * 64 + lane][q * 2];
        uint32_t rw1 = adj[h * 64 + lane][q * 2 + 1];
        uint32_t myLo = 0, myHi = 0;
        #pragma unroll
        for (int cc = 0; cc < 64; ++cc) {
            uint32_t w = (cc < 32) ? rw0 : rw1;
            unsigned long long m = __ballot((w >> (cc & 31)) & 1u);
            if (lane == cc) { myLo = (uint32_t)m; myHi = (uint32_t)(m >> 32); }
        }
        adjT[q * 64 + lane][2 * h]     = myLo;
        adjT[q * 64 + lane][2 * h + 1] = myHi;
    }
    __syncthreads();   // adjT ready

    // Per-node registers for Kahn (nodes on threads 0..127)
    uint32_t cT0 = 0, cT1 = 0, cT2 = 0, cT3 = 0;
    int  indeg = 0;
    bool validT = false;
    if (t < KN) {
        cT0 = adjT[t][0]; cT1 = adjT[t][1]; cT2 = adjT[t][2]; cT3 = adjT[t][3];
        validT = (validW[t >> 5] >> (t & 31)) & 1u;
        indeg = validT ? (__popc(cT0) + __popc(cT1) + __popc(cT2) + __popc(cT3)) : 0;
    }

    // ================= phase bodies (as lambdas; block-uniform call order) ====
    auto rel_expand = [&]() {
        // Bit->float via multiply-spread into a byte-packed word; clang emits
        // v_cvt_f32_ubyte{0..3} for (float)(uint8_t)(x>>8k).
        #pragma unroll
        for (int m = 0; m < 16; ++m) {
            int q  = t + 256 * m;        // float4 index 0..4095
            int i  = q >> 5;             // row
            int j0 = (q & 31) * 4;       // starting col
            int iw = j0 >> 5, sh = j0 & 31;
            uint32_t wij = adj[i][iw];           // cb[i][j0..]
            uint32_t wti = adjT[i][iw];          // cb[j0..][i]
            uint32_t a4 = (wij >> sh) & 0xFu;
            uint32_t b4 = (wti >> sh) & 0xFu;
            uint32_t packed = ((a4 * 0x00204081u) & 0x01010101u)
                            | (((b4 * 0x00204081u) & 0x01010101u) << 1);
            vfloat4 o;
            o.x = (float)(uint8_t)(packed);
            o.y = (float)(uint8_t)(packed >> 8);
            o.z = (float)(uint8_t)(packed >> 16);
            o.w = (float)(uint8_t)(packed >> 24);
            __builtin_nontemporal_store(o, ((vfloat4*)relp) + q);
        }
    };

    auto logic_phase = [&]() {
        // Edit-token scan: min linear index of differing upper-triangle pair
        for (int idx = t; idx < 512; idx += 256) {
            int i = idx >> 2, k = idx & 3;
            uint32_t diff = adj[i][k] ^ baseB[i][k];
            if (diff) {
                int base = k * 32;
                uint32_t up, low;
                if (i < base)            { up = diff; low = 0u; }
                else if (i >= base + 31) { up = 0u; low = (i > base + 31) ? diff : (diff & 0x7fffffffu); }
                else {
                    int s = i - base;    // 1..30
                    up  = diff & (0xffffffffu << (s + 1));
                    low = diff & ((1u << s) - 1u);
                }
                int c1 = 0x7fffffff, c2 = 0x7fffffff;
                if (up)  c1 = (i << 7) | (base + __builtin_ctz(up));
                if (low) { int cc2 = base + __builtin_ctz(low); c2 = (cc2 << 7) | i; }
                int cm = min(c1, c2);
                if (cm != 0x7fffffff) atomicMin(&minIdx, cm);
            }
        }
        __syncthreads();   // minIdx final

        // Token write
        if (t == 0) {
            float* tok = out + TOK_OFF + (size_t)bc * 4;
            int mi = minIdx;
            if (mi != 0x7fffffff) {
                int i = mi >> 7, j = mi & 127;
                uint32_t b_ij = (baseB[i][j >> 5] >> (j & 31)) & 1u;
                uint32_t b_ji = (baseB[j][i >> 5] >> (i & 31)) & 1u;
                uint32_t c_ij = (adj[i][j >> 5] >> (j & 31)) & 1u;
                uint32_t c_ji = (adj[j][i >> 5] >> (i & 31)) & 1u;
                int prev = (b_ij && !b_ji) ? 1 : ((b_ji && !b_ij) ? 2 : 0);
                int nxt  = (c_ij && !c_ji) ? 1 : ((c_ji && !c_ij) ? 2 : 0);
                tok[0] = (float)i; tok[1] = (float)j; tok[2] = (float)prev; tok[3] = (float)nxt;
            } else {
                tok[0] = 0.f; tok[1] = 0.f; tok[2] = 0.f; tok[3] = 0.f;
            }
        }

        // Kahn peeling: dec via popc of column masks (early-exit = fixed point)
        bool removed = false;
        for (int it = 0; it < KN; ++it) {
            bool rem = (t < KN) && validT && !removed && (indeg == 0);
            unsigned long long m = __ballot(rem);
            if (wave < 2 && lane == 0) {
                remW[wave * 2]     = (uint32_t)m;
                remW[wave * 2 + 1] = (uint32_t)(m >> 32);
            }
            __syncthreads();
            uint32_t r0 = remW[0], r1 = remW[1], r2 = remW[2], r3 = remW[3];
            if ((r0 | r1 | r2 | r3) == 0u) break;
            if (t < 4) removedW[t] |= remW[t];
            if (t < KN) {
                indeg -= __popc(r0 & cT0) + __popc(r1 & cT1) +
                         __popc(r2 & cT2) + __popc(r3 & cT3);
                removed = removed || rem;
            }
            __syncthreads();
        }
        __syncthreads();

        if (t == 0) {
            int rc = __popc(removedW[0]) + __popc(removedW[1]) + __popc(removedW[2]) + __popc(removedW[3]);
            int vc = __popc(validW[0]) + __popc(validW[1]) + __popc(validW[2]) + __popc(validW[3]);
            out[ACY_OFF + bc] = ((rc == vc) || (vc <= 1)) ? 1.0f : 0.0f;
        }
    };

    // Parity stagger (block-uniform branch: __syncthreads inside is safe)
    if ((bc & 1) == 0) {
        rel_expand();
        logic_phase();
    } else {
        logic_phase();
        rel_expand();
    }
}

extern "C" void kernel_launch(void* const* d_in, const int* in_sizes, int n_in,
                              void* d_out, int out_size, void* d_ws, size_t ws_size,
                              hipStream_t stream) {
    const float* A_t  = (const float*)d_in[0];
    const float* cand = (const float*)d_in[1];
    const float* feat = (const float*)d_in[2];
    const float* mask = (const float*)d_in[3];
    float* out = (float*)d_out;
    uint32_t* bits = (uint32_t*)d_ws;   // B*K*4 words = 8 KB

    prep_kernel<<<1024, 256, 0, stream>>>(A_t, feat, bits, out);
    main_kernel<<<BATCH * CAND, 256, 0, stream>>>(cand, mask, bits, out);
}